// Round 11
// baseline (313.217 us; speedup 1.0000x reference)
//
#include <hip/hip_runtime.h>
#include <math.h>

#define NB 512
#define LIN 640
#define NLEADS 3
#define L1O 322
#define L2O 161
#define L3O 79
#define C1N 64
#define C2N 128
#define C3N 256
#define FLATSZ 20224   // 256*79
#define NUMK 100
#define DIMK 5
#define SPLITK 16

typedef __attribute__((ext_vector_type(8))) short short8;
typedef __attribute__((ext_vector_type(4))) float f32x4;

__device__ __forceinline__ unsigned short f2bf(float x){
  unsigned u = __builtin_bit_cast(unsigned, x);
  unsigned r = u + 0x7FFFu + ((u >> 16) & 1u);
  return (unsigned short)(r >> 16);
}
__device__ __forceinline__ float bf2f(unsigned short x){
  unsigned u = ((unsigned)x) << 16;
  return __builtin_bit_cast(float, u);
}

__device__ __forceinline__ float block_reduce_sum(float val, float* red){
#pragma unroll
  for(int off=32; off>0; off>>=1) val += __shfl_down(val, off, 64);
  int lane = threadIdx.x & 63;
  int wv = threadIdx.x >> 6;
  if(lane==0) red[wv] = val;
  __syncthreads();
  int nw = blockDim.x >> 6;
  float r = red[0];
  for(int i=1;i<nw;i++) r += red[i];
  __syncthreads();
  return r;
}

// ---------- SN pass 1 ----------
__global__ __launch_bounds__(256)
void sn_pass1(const float* __restrict__ w1, const float* __restrict__ u1,
              const float* __restrict__ w2, const float* __restrict__ u2,
              const float* __restrict__ w3, const float* __restrict__ u3,
              float* __restrict__ v_all, float* __restrict__ ss){
  __shared__ float red[4];
  int b = blockIdx.x, tid = threadIdx.x;
  const float* w; const float* u; int O, C, off, c, widx;
  if(b==0){ w=w1; u=u1; O=64;  C=15;   off=0;   c=tid;            widx=0; }
  else if(b<3){ w=w2; u=u2; O=128; C=448; off=16;  c=(b-1)*256+tid; widx=1; }
  else { w=w3; u=u3; O=256; C=1152; off=464; c=(b-3)*256+tid;      widx=2; }
  float vv = 0.f;
  if(c < C){
    for(int o=0;o<O;o+=4){
      vv += w[(o+0)*C+c]*u[o+0] + w[(o+1)*C+c]*u[o+1]
          + w[(o+2)*C+c]*u[o+2] + w[(o+3)*C+c]*u[o+3];
    }
    v_all[off + c] = vv;
  }
  float ps = (c < C) ? vv*vv : 0.f;
  float tot = block_reduce_sum(ps, red);
  if(tid==0) atomicAdd(&ss[widx], tot);
}

// ---------- SN pass 2 ----------
__global__ __launch_bounds__(256)
void sn_pass2(const float* __restrict__ w1, const float* __restrict__ w2,
              const float* __restrict__ w3, const float* __restrict__ v_all,
              float* __restrict__ Sun){
  int b = blockIdx.x, tid = threadIdx.x;
  int lane = tid & 63, wv = tid >> 6;
  const float* w; int C, off, o, widx;
  if(b < 16){ w=w1; C=15;   off=0;   o=b*4+wv;      widx=0; }
  else if(b < 48){ w=w2; C=448; off=16;  o=(b-16)*4+wv; widx=1; }
  else { w=w3; C=1152; off=464; o=(b-48)*4+wv;          widx=2; }
  float t = 0.f;
  for(int c=lane; c<C; c+=64) t += w[o*C+c]*v_all[off+c];
#pragma unroll
  for(int s=32; s>0; s>>=1) t += __shfl_down(t, s, 64);
  if(lane==0) atomicAdd(&Sun[widx], t*t);
}

__global__ void sn_final(const float* __restrict__ ss, const float* __restrict__ Sun,
                         float* __restrict__ scale){
  int tid = threadIdx.x;
  if(tid < 3){
    float inv = 1.f/(sqrtf(ss[tid])+1e-12f);
    float S = Sun[tid]*inv*inv;
    scale[tid] = (sqrtf(S)+1e-12f)/S;
  }
}

// ---------- weight prep: w1 padded; w2 K-PERMUTED (k'=r*64+i); w3 K-PERMUTED (k'=r*128+i) ----------
__global__ void wprep_kernel(const float* __restrict__ w1, const float* __restrict__ w2,
                             const float* __restrict__ w3, const float* __restrict__ scale,
                             unsigned short* __restrict__ w1p, unsigned short* __restrict__ w2p,
                             unsigned short* __restrict__ w3p){
  int idx = blockIdx.x*256 + threadIdx.x;
  float s1 = scale[0], s2 = scale[1], s3 = scale[2];
  if(idx < C1N*32){
    int o = idx >> 5, kk = idx & 31;
    w1p[idx] = (kk < 15) ? f2bf(w1[o*15+kk]*s1) : 0;
  }
  if(idx < C2N*448){
    int o = idx / 448, k2 = idx - o*448;
    int r = k2 >> 6, i = k2 & 63;
    w2p[idx] = f2bf(w2[o*448 + i*7 + r]*s2);
  }
  if(idx < C3N*1152){
    int o = idx / 1152, k2 = idx - o*1152;
    int r = k2 >> 7, i = k2 & 127;
    w3p[idx] = f2bf(w3[o*1152 + i*9 + r]*s3);
  }
}

// ---------- fused conv1+conv2 MFMA, t-split 2 ways; K-permuted conv2, barrier-lite ----------
__global__ __launch_bounds__(256, 4)
void conv12_mfma(const float* __restrict__ ecg, const unsigned short* __restrict__ w1p,
                 const float* __restrict__ b1, const unsigned short* __restrict__ w2p,
                 const float* __restrict__ b2, unsigned short* __restrict__ y2t){
  __shared__ unsigned short slabs[13600];   // even [100][68] @0, odd @6800; reused as trans[96][136]
  __shared__ unsigned short B1s[6656];      // 208*32 — conv1 im2col
  int n = blockIdx.x, tile = blockIdx.y, tid = threadIdx.x;
  int lane = tid & 63, w = tid >> 6;
  int c0    = tile ? 189 : 0;
  int tbase = tile ? 96  : 0;
  int suboff= tile ? -94 : 2;

  {
    uint4 z = {0u,0u,0u,0u};
    uint4* zd = (uint4*)slabs;
#pragma unroll
    for(int q=0;q<7;q++){
      int f = q*256 + tid;
      if(f < 1700) zd[f] = z;
    }
  }
  const float* eb = ecg + (size_t)n*LIN*NLEADS;
#pragma unroll
  for(int q=0;q<26;q++){
    int e = q*256 + tid;
    int tp = e >> 5, kk = e & 31;
    unsigned short v = 0;
    if(kk < 15){
      int i = kk/5, r = kk - i*5;
      int p = 2*(c0 + tp) - 4 + r;
      if((unsigned)p < (unsigned)LIN) v = f2bf(eb[p*NLEADS + i]);
    }
    B1s[tp*32 + kk] = v;
  }
  __syncthreads();

  // conv1 MFMA -> parity slabs (sub<100 guard: see r9 fix)
  {
    short8 a1 = *(const short8*)(w1p + ((w*16 + (lane&15))<<5) + (lane>>4)*8);
    f32x4 zero = {0.f,0.f,0.f,0.f};
#pragma unroll
    for(int half=0; half<2; half++){
      int nt0 = half*7, ntc = half ? 6 : 7;
      f32x4 c1[7];
      for(int j=0;j<ntc;j++){
        short8 b = *(const short8*)(B1s + (((nt0+j)*16 + (lane&15))<<5) + (lane>>4)*8);
        c1[j] = __builtin_amdgcn_mfma_f32_16x16x32_bf16(a1, b, zero, 0, 0, 0);
      }
#pragma unroll
      for(int reg=0;reg<4;reg++){
        int o = w*16 + (lane>>4)*4 + reg;
        float bias = b1[o];
        for(int j=0;j<ntc;j++){
          int tp = (nt0+j)*16 + (lane&15);
          int t1 = c0 + tp;
          int sub = (t1>>1) + suboff;
          if(t1 < L1O && sub < 100){
            float v = c1[j][reg] + bias;
            v = v>=0.f ? v : 0.2f*v;
            slabs[((t1&1)?6800:0) + sub*68 + o] = f2bf(v);
          }
        }
      }
    }
  }
  __syncthreads();

  // conv2 K-loop: barrier-free
  f32x4 zero = {0.f,0.f,0.f,0.f};
  f32x4 acc[2][6];
#pragma unroll
  for(int i=0;i<2;i++)
#pragma unroll
    for(int j=0;j<6;j++) acc[i][j] = zero;

  const unsigned short* w2base = w2p + ((size_t)(w*2*16 + (lane&15)))*448 + (lane>>4)*8;
  short8 a_cur[2];
  a_cur[0] = *(const short8*)(w2base);
  a_cur[1] = *(const short8*)(w2base + 16*448);

  for(int ck=0; ck<14; ck++){
    short8 a_nxt[2];
    if(ck < 13){
      a_nxt[0] = *(const short8*)(w2base + (ck+1)*32);
      a_nxt[1] = *(const short8*)(w2base + 16*448 + (ck+1)*32);
    }
    int r = ck >> 1, i0 = (ck & 1)*32;
    int p = (r+1) & 1;
    int m = ((r-3) - p) >> 1;
    int base = (p?6800:0) + (m+2 + (lane&15))*68 + i0 + (lane>>4)*8;
    short8 b[6];
#pragma unroll
    for(int nt=0;nt<6;nt++)
      b[nt] = *(const short8*)(slabs + base + nt*16*68);
#pragma unroll
    for(int mm=0;mm<2;mm++)
#pragma unroll
      for(int nt=0;nt<6;nt++)
        acc[mm][nt] = __builtin_amdgcn_mfma_f32_16x16x32_bf16(a_cur[mm], b[nt], acc[mm][nt], 0, 0, 0);
    if(ck < 13){ a_cur[0] = a_nxt[0]; a_cur[1] = a_nxt[1]; }
  }

  __syncthreads();
  unsigned short* trans = slabs;
#pragma unroll
  for(int mm=0;mm<2;mm++){
#pragma unroll
    for(int reg=0;reg<4;reg++){
      int o = (w*2+mm)*16 + (lane>>4)*4 + reg;
      float bias = b2[o];
#pragma unroll
      for(int nt=0;nt<6;nt++){
        int tl = nt*16 + (lane&15);
        int t = tbase + tl;
        if(t < L2O){
          float v = acc[mm][nt][reg] + bias;
          v = v>=0.f ? v : 0.2f*v;
          trans[tl*136 + o] = f2bf(v);
        }
      }
    }
  }
  __syncthreads();
  {
    int rows = tile ? 65 : 96;
    uint4* dstg = (uint4*)(y2t + (size_t)n*20608 + tbase*128);
#pragma unroll
    for(int q=0;q<6;q++){
      int f = q*256 + tid;
      int row = f >> 4, c8 = f & 15;
      if(row < rows)
        dstg[row*16 + c8] = *(const uint4*)(trans + row*136 + c8*8);
    }
  }
}

// ---------- conv3 MFMA: M-split 2x, 2-deep A prefetch, barrier-free K-loop ----------
// grid (NB, 2): block h handles o in [h*128, h*128+128); wave owns 32 rows (2 m-tiles)
__global__ __launch_bounds__(256, 4)
void conv3_mfma(const unsigned short* __restrict__ y2t, const unsigned short* __restrict__ w3p,
                const float* __restrict__ b3, unsigned short* __restrict__ flatbf){
  __shared__ unsigned short lds[22712];  // even slab 84*136 @0; odd slab 83*136 @11424
  int n = blockIdx.x, h = blockIdx.y, tid = threadIdx.x;
  int lane = tid & 63, w = tid >> 6;

  if(tid < 136){
    lds[tid] = 0;
    lds[82*136 + tid] = 0;
    lds[83*136 + tid] = 0;
    lds[11424 + tid] = 0;
    lds[11424 + 81*136 + tid] = 0;
    lds[11424 + 82*136 + tid] = 0;
  }
  {
    const uint4* src = (const uint4*)(y2t + (size_t)n*20608);
#pragma unroll
    for(int q=0;q<11;q++){
      int f = q*256 + tid;
      if(f < 2576){
        int g = f >> 4, c8 = f & 15;
        int sub = g >> 1, p = g & 1;
        *(uint4*)(lds + (p ? 11424 : 0) + (sub+1)*136 + c8*8) = src[(size_t)g*16 + c8];
      }
    }
  }

  f32x4 zero = {0.f,0.f,0.f,0.f};
  f32x4 acc[2][5];
#pragma unroll
  for(int i=0;i<2;i++)
#pragma unroll
    for(int j=0;j<5;j++) acc[i][j] = zero;

  // A rows: o = h*128 + w*32 + mm*16 + (lane&15)
  const unsigned short* wbase = w3p + ((size_t)(h*128 + w*32) + (lane&15))*1152 + (lane>>4)*8;
  short8 a0[2], a1[2];
  a0[0] = *(const short8*)(wbase);
  a0[1] = *(const short8*)(wbase + 16*1152);
  a1[0] = *(const short8*)(wbase + 32);
  a1[1] = *(const short8*)(wbase + 16*1152 + 32);
  __syncthreads();

#pragma unroll
  for(int ck2=0; ck2<18; ck2++){
    // --- even chunk: ck = 2*ck2, uses a0, prefetches ck+2 into a0 ---
    {
      int ck = 2*ck2;
      int r = ck >> 2, i0 = (ck & 3) * 32;
      int cbase = ((r & 1) ? 11424 : 0) + (r >> 1)*136 + i0 + (lane>>4)*8;
      short8 b[5];
#pragma unroll
      for(int nt=0;nt<5;nt++)
        b[nt] = *(const short8*)(lds + cbase + (nt*16 + (lane&15))*136);
#pragma unroll
      for(int mm=0;mm<2;mm++)
#pragma unroll
        for(int nt=0;nt<5;nt++)
          acc[mm][nt] = __builtin_amdgcn_mfma_f32_16x16x32_bf16(a0[mm], b[nt], acc[mm][nt], 0, 0, 0);
      if(ck + 2 < 36){
        int kc = (ck+2)*32;
        a0[0] = *(const short8*)(wbase + kc);
        a0[1] = *(const short8*)(wbase + 16*1152 + kc);
      }
    }
    // --- odd chunk: ck = 2*ck2+1, uses a1, prefetches ck+2 into a1 ---
    {
      int ck = 2*ck2 + 1;
      int r = ck >> 2, i0 = (ck & 3) * 32;
      int cbase = ((r & 1) ? 11424 : 0) + (r >> 1)*136 + i0 + (lane>>4)*8;
      short8 b[5];
#pragma unroll
      for(int nt=0;nt<5;nt++)
        b[nt] = *(const short8*)(lds + cbase + (nt*16 + (lane&15))*136);
#pragma unroll
      for(int mm=0;mm<2;mm++)
#pragma unroll
        for(int nt=0;nt<5;nt++)
          acc[mm][nt] = __builtin_amdgcn_mfma_f32_16x16x32_bf16(a1[mm], b[nt], acc[mm][nt], 0, 0, 0);
      if(ck + 2 < 36){
        int kc = (ck+2)*32;
        a1[0] = *(const short8*)(wbase + kc);
        a1[1] = *(const short8*)(wbase + 16*1152 + kc);
      }
    }
  }

#pragma unroll
  for(int mm=0;mm<2;mm++){
#pragma unroll
    for(int reg=0;reg<4;reg++){
      int o = h*128 + w*32 + mm*16 + (lane>>4)*4 + reg;
      float bias = b3[o];
#pragma unroll
      for(int nt=0;nt<5;nt++){
        int t = nt*16 + (lane&15);
        if(t < L3O){
          float v = acc[mm][nt][reg] + bias;
          v = v>=0.f ? v : 0.2f*v;
          flatbf[(size_t)n*FLATSZ + o*L3O + t] = f2bf(v);
        }
      }
    }
  }
}

// ---------- transpose + bf16: mbwT[n][k] ----------
__global__ __launch_bounds__(256)
void mbw_transpose(const float* __restrict__ mbw, unsigned short* __restrict__ mbwT){
  __shared__ unsigned short tile[32][36];
  int k0 = blockIdx.x*32, n0 = blockIdx.y*32, tid = threadIdx.x;
  int r = tid >> 3, c4 = (tid & 7) * 4;
  int nbase = n0 + c4;
  if(nbase + 3 < 500){
    float4 v = *(const float4*)(mbw + (size_t)(k0+r)*500 + nbase);
    tile[r][c4+0] = f2bf(v.x);
    tile[r][c4+1] = f2bf(v.y);
    tile[r][c4+2] = f2bf(v.z);
    tile[r][c4+3] = f2bf(v.w);
  } else {
#pragma unroll
    for(int j=0;j<4;j++){
      int nn = nbase + j;
      float v = (nn < 500) ? mbw[(size_t)(k0+r)*500 + nn] : 0.f;
      tile[r][c4+j] = f2bf(v);
    }
  }
  __syncthreads();
  int nl = tid >> 3, kq = (tid & 7) * 4;
  unsigned short t0 = tile[kq+0][nl], t1 = tile[kq+1][nl];
  unsigned short t2 = tile[kq+2][nl], t3 = tile[kq+3][nl];
  uint2 p;
  p.x = (unsigned)t0 | ((unsigned)t1 << 16);
  p.y = (unsigned)t2 | ((unsigned)t3 << 16);
  *(uint2*)(mbwT + (size_t)(n0+nl)*FLATSZ + k0 + kq) = p;
}

// ---------- split-K MFMA GEMM ----------
__global__ __launch_bounds__(256)
void mb_gemm_mfma(const unsigned short* __restrict__ flatbf, const unsigned short* __restrict__ mbwT,
                  float* __restrict__ part){
  __shared__ unsigned short As[64*32];
  __shared__ unsigned short Bs[64*32];
  int tid = threadIdx.x;
  int lane = tid & 63, w = tid >> 6;
  int m0 = blockIdx.x*64, n0 = blockIdx.y*64, bz = blockIdx.z;
  int t_start = bz*39 + (bz<8 ? bz : 8);
  int t_count = 39 + (bz<8 ? 1 : 0);
  int k0 = t_start*32;
  f32x4 zero = {0.f,0.f,0.f,0.f};
  f32x4 acc[4];
#pragma unroll
  for(int i=0;i<4;i++) acc[i] = zero;
  int arow = tid >> 2, acol = (tid & 3) * 8;
  for(int t=0; t<t_count; t++, k0+=32){
    __syncthreads();
    ((uint4*)As)[tid] = *(const uint4*)(flatbf + (size_t)(m0+arow)*FLATSZ + k0 + acol);
    ((uint4*)Bs)[tid] = *(const uint4*)(mbwT  + (size_t)(n0+arow)*FLATSZ + k0 + acol);
    __syncthreads();
    short8 a = *(const short8*)(As + (w*16 + (lane&15))*32 + (lane>>4)*8);
#pragma unroll
    for(int nt=0;nt<4;nt++){
      short8 b = *(const short8*)(Bs + (nt*16 + (lane&15))*32 + (lane>>4)*8);
      acc[nt] = __builtin_amdgcn_mfma_f32_16x16x32_bf16(a, b, acc[nt], 0, 0, 0);
    }
  }
  float* po = part + (size_t)bz*NB*500;
#pragma unroll
  for(int nt=0;nt<4;nt++){
#pragma unroll
    for(int reg=0;reg<4;reg++){
      int m = m0 + w*16 + (lane>>4)*4 + reg;
      int c = n0 + nt*16 + (lane&15);
      if(c < 500) po[(size_t)m*500 + c] = acc[nt][reg];
    }
  }
}

// ---------- reduce partials -> actT[c][n] ----------
__global__ void mb_reduce_kernel(const float* __restrict__ part, float* __restrict__ actT){
  int idx = blockIdx.x*256 + threadIdx.x;   // n*500+c
  float s = 0.f;
#pragma unroll
  for(int z=0;z<SPLITK;z++) s += part[(size_t)z*NB*500 + idx];
  int n = idx/500, c = idx - n*500;
  actT[(size_t)c*NB + n] = s;
}

// ---------- minibatch features ----------
__global__ __launch_bounds__(256)
void feats_kernel(const float* __restrict__ actT, float* __restrict__ feats){
  __shared__ float ash[4][50];
  __shared__ float pred[4][4];
  int i0 = blockIdx.x*4, k0 = blockIdx.y*10;
  int tid = threadIdx.x, lane = tid & 63, wv = tid >> 6;
  if(tid < 200){
    int ii = tid/50, c = tid - ii*50;
    ash[ii][c] = actT[(size_t)(k0*5+c)*NB + i0 + ii];
  }
  __syncthreads();
  const float LOG2E = 1.4426950408889634f;
  int j1 = tid, j2 = tid + 256;
  for(int kk=0; kk<10; kk++){
    const float* r0 = actT + (size_t)(k0+kk)*5*NB;
    float xa0=r0[j1], xa1=r0[NB+j1], xa2=r0[2*NB+j1], xa3=r0[3*NB+j1], xa4=r0[4*NB+j1];
    float xb0=r0[j2], xb1=r0[NB+j2], xb2=r0[2*NB+j2], xb3=r0[3*NB+j2], xb4=r0[4*NB+j2];
    float f[4];
#pragma unroll
    for(int ii=0; ii<4; ii++){
      float a0=ash[ii][kk*5+0], a1=ash[ii][kk*5+1], a2=ash[ii][kk*5+2],
            a3=ash[ii][kk*5+3], a4=ash[ii][kk*5+4];
      float la = fabsf(xa0-a0)+fabsf(xa1-a1)+fabsf(xa2-a2)+fabsf(xa3-a3)+fabsf(xa4-a4);
      float lb = fabsf(xb0-a0)+fabsf(xb1-a1)+fabsf(xb2-a2)+fabsf(xb3-a3)+fabsf(xb4-a4);
      f[ii] = exp2f(-LOG2E*la) + exp2f(-LOG2E*lb);
    }
#pragma unroll
    for(int ii=0; ii<4; ii++){
      float v = f[ii];
#pragma unroll
      for(int s=32; s>0; s>>=1) v += __shfl_down(v, s, 64);
      if(lane==0) pred[wv][ii] = v;
    }
    __syncthreads();
    if(tid < 4){
      float v = pred[0][tid] + pred[1][tid] + pred[2][tid] + pred[3][tid];
      feats[(size_t)(i0+tid)*NUMK + k0 + kk] = v;
    }
    __syncthreads();
  }
}

// ---------- final ----------
__global__ void final_kernel(const unsigned short* __restrict__ flatbf, const float* __restrict__ feats,
                             const int* __restrict__ condition, const float* __restrict__ emb,
                             const float* __restrict__ cond_w, const float* __restrict__ cond_b,
                             const float* __restrict__ fc_w, const float* __restrict__ fc_b,
                             float* __restrict__ out){
  __shared__ float red[4];
  int n = blockIdx.x, tid = threadIdx.x;
  float s = 0.f;
  const unsigned short* fr = flatbf + (size_t)n*FLATSZ;
  for(int q=tid; q<FLATSZ/8; q+=256){
    uint4 u = *(const uint4*)(fr + q*8);
    float4 wa = *(const float4*)(fc_w + q*8);
    float4 wb = *(const float4*)(fc_w + q*8 + 4);
    s += bf2f((unsigned short)(u.x & 0xffff))*wa.x + bf2f((unsigned short)(u.x >> 16))*wa.y
       + bf2f((unsigned short)(u.y & 0xffff))*wa.z + bf2f((unsigned short)(u.y >> 16))*wa.w
       + bf2f((unsigned short)(u.z & 0xffff))*wb.x + bf2f((unsigned short)(u.z >> 16))*wb.y
       + bf2f((unsigned short)(u.w & 0xffff))*wb.z + bf2f((unsigned short)(u.w >> 16))*wb.w;
  }
  for(int k=tid;k<NUMK;k+=256) s += feats[n*NUMK+k]*fc_w[FLATSZ+k];
  float ce = emb[condition[n]];
  for(int j=tid;j<50;j+=256) s += (ce*cond_w[j]+cond_b[j])*fc_w[FLATSZ+NUMK+j];
  s = block_reduce_sum(s, red);
  if(tid==0) out[n] = s + fc_b[0];
}

extern "C" void kernel_launch(void* const* d_in, const int* in_sizes, int n_in,
                              void* d_out, int out_size, void* d_ws, size_t ws_size,
                              hipStream_t stream) {
  const float* ecg   = (const float*)d_in[0];
  const int*   cond  = (const int*)  d_in[1];
  const float* w1    = (const float*)d_in[2];
  const float* b1    = (const float*)d_in[3];
  const float* u1    = (const float*)d_in[4];
  const float* w2    = (const float*)d_in[5];
  const float* b2    = (const float*)d_in[6];
  const float* u2    = (const float*)d_in[7];
  const float* w3    = (const float*)d_in[8];
  const float* b3    = (const float*)d_in[9];
  const float* u3    = (const float*)d_in[10];
  const float* emb   = (const float*)d_in[11];
  const float* condw = (const float*)d_in[12];
  const float* condb = (const float*)d_in[13];
  const float* mbw   = (const float*)d_in[14];
  const float* fcw   = (const float*)d_in[15];
  const float* fcb   = (const float*)d_in[16];

  float* ws = (float*)d_ws;
  float* scale = ws;                                      // 0..16
  float* ssbuf = ws + 16;
  float* Sunbuf= ws + 24;
  float* v_all = ws + 32;                                 // ends 1648
  unsigned short* w1p  = (unsigned short*)(ws + 1648);    // -> 2672
  unsigned short* w2p  = (unsigned short*)(ws + 2672);    // -> 31344
  unsigned short* w3p  = (unsigned short*)(ws + 31344);   // -> 178800
  unsigned short* y2t  = (unsigned short*)(ws + 178800);  // 5,275,648 f -> 5,454,448
  unsigned short* mbwT = (unsigned short*)(ws + 178800);  // overlays y2t (dead after conv3)
  float* part  = ws + 5454448;                            // 4,096,000 f -> 9,550,448
  float* actT  = ws + 9550448;                            // 256,000 f -> 9,806,448
  float* feats = ws + 9806448;                            // 51,200 f -> 9,857,648
  unsigned short* flatbf = (unsigned short*)(ws + 9857648); // 5,177,344 f -> ends 15,034,992

  hipMemsetAsync((char*)d_ws + 64, 0, 64, stream);   // zero ssbuf/Sunbuf
  sn_pass1<<<8, 256, 0, stream>>>(w1,u1,w2,u2,w3,u3, v_all, ssbuf);
  sn_pass2<<<112, 256, 0, stream>>>(w1,w2,w3, v_all, Sunbuf);
  sn_final<<<1, 64, 0, stream>>>(ssbuf, Sunbuf, scale);
  wprep_kernel<<<1152, 256, 0, stream>>>(w1, w2, w3, scale, w1p, w2p, w3p);
  conv12_mfma<<<dim3(NB,2), 256, 0, stream>>>(ecg, w1p, b1, w2p, b2, y2t);
  conv3_mfma<<<dim3(NB,2), 256, 0, stream>>>(y2t, w3p, b3, flatbf);
  mbw_transpose<<<dim3(632,16), 256, 0, stream>>>(mbw, mbwT);
  mb_gemm_mfma<<<dim3(8,8,SPLITK), 256, 0, stream>>>(flatbf, mbwT, part);
  mb_reduce_kernel<<<1000, 256, 0, stream>>>(part, actT);
  feats_kernel<<<dim3(128,10), 256, 0, stream>>>(actT, feats);
  final_kernel<<<NB, 256, 0, stream>>>(flatbf, feats, cond, emb, condw, condb, fcw, fcb, (float*)d_out);
}